// Round 3
// baseline (7663.428 us; speedup 1.0000x reference)
//
#include <hip/hip_runtime.h>
#include <math.h>

constexpr int B = 2;
constexpr int F = 2112;
constexpr int D = 1024;
constexpr int H = 8;
constexpr int DH = 64;
constexpr int INNER = H * DH;      // 512
constexpr int NL = 721;
constexpr int NL_PAD = 768;
constexpr int MLAT = B * NL;       // 1442
constexpr int MLAT_PAD = 1536;     // 12*128
constexpr int VD = 64;
constexpr int DEPTH = 6;
constexpr int FN = F + NL;         // 2833
constexpr int FN_PAD = 2880;       // 45 * 64
constexpr float EPS = 1e-5f;

typedef __bf16 bf16x8 __attribute__((ext_vector_type(8)));
typedef float  f32x4  __attribute__((ext_vector_type(4)));

static __device__ __forceinline__ unsigned short f2bf(float f)
{
    union { float f; unsigned int u; } x; x.f = f;
    unsigned int r = x.u + 0x7FFFu + ((x.u >> 16) & 1u);   // RNE
    return (unsigned short)(r >> 16);
}

__device__ __forceinline__ void gload_lds16(const unsigned short* g, unsigned short* l)
{
    __builtin_amdgcn_global_load_lds(
        (const __attribute__((address_space(1))) unsigned int*)g,
        (__attribute__((address_space(3))) unsigned int*)l, 16, 0, 0);
}

// ---------------- block reduce (sum, sumsq) over 256 threads ----------------
__device__ __forceinline__ void block_reduce_2(float& s, float& ss, float* red)
{
#pragma unroll
    for (int off = 32; off; off >>= 1) {
        s  += __shfl_xor(s, off);
        ss += __shfl_xor(ss, off);
    }
    int wv = threadIdx.x >> 6;
    if ((threadIdx.x & 63) == 0) { red[wv] = s; red[4 + wv] = ss; }
    __syncthreads();
    s  = red[0] + red[1] + red[2] + red[3];
    ss = red[4] + red[5] + red[6] + red[7];
}

// ------------- x + spatial_emb + frame_emb, then row-normalize --------------
__global__ __launch_bounds__(256) void emb_ln_kernel(
    const float* __restrict__ x, const float* __restrict__ sp_emb,
    const float* __restrict__ fr_emb, float* __restrict__ xhat)
{
    __shared__ float red[8];
    int r = blockIdx.x;            // r = b*F + j
    int j = r % F;
    int t = threadIdx.x;
    const float4* xr = (const float4*)(x + (long)r * D);
    int spr = (j < VD) ? j : VD;
    int frr = (j < VD) ? 0 : (j - VD + 1);
    const float4* sp4 = (const float4*)(sp_emb + (long)spr * D);
    const float4* fr4 = (const float4*)(fr_emb + (long)frr * D);
    float4 v = xr[t], a = sp4[t], c = fr4[t];
    v.x += a.x + c.x; v.y += a.y + c.y; v.z += a.z + c.z; v.w += a.w + c.w;
    float s  = v.x + v.y + v.z + v.w;
    float ss = v.x*v.x + v.y*v.y + v.z*v.z + v.w*v.w;
    block_reduce_2(s, ss, red);
    float mean = s * (1.0f / D);
    float var  = ss * (1.0f / D) - mean * mean;
    float rstd = rsqrtf(var + EPS);
    float4 o;
    o.x = (v.x - mean) * rstd; o.y = (v.y - mean) * rstd;
    o.z = (v.z - mean) * rstd; o.w = (v.w - mean) * rstd;
    ((float4*)(xhat + (long)r * D))[t] = o;
}

// --------- row-normalize with affine -> bf16 (for GEMM A operands) ----------
__global__ __launch_bounds__(256) void rownorm_affine_bf16_kernel(
    const float* __restrict__ in, const float* __restrict__ g,
    const float* __restrict__ b, unsigned short* __restrict__ out)
{
    __shared__ float red[8];
    int r = blockIdx.x;
    int t = threadIdx.x;
    float4 v = ((const float4*)(in + (long)r * D))[t];
    float s  = v.x + v.y + v.z + v.w;
    float ss = v.x*v.x + v.y*v.y + v.z*v.z + v.w*v.w;
    block_reduce_2(s, ss, red);
    float mean = s * (1.0f / D);
    float var  = ss * (1.0f / D) - mean * mean;
    float rstd = rsqrtf(var + EPS);
    float4 g4 = ((const float4*)g)[t];
    float4 b4 = ((const float4*)b)[t];
    ushort4 o;
    o.x = f2bf((v.x - mean) * rstd * g4.x + b4.x);
    o.y = f2bf((v.y - mean) * rstd * g4.y + b4.y);
    o.z = f2bf((v.z - mean) * rstd * g4.z + b4.z);
    o.w = f2bf((v.w - mean) * rstd * g4.w + b4.w);
    ((ushort4*)(out + (long)r * D))[t] = o;
}

// --------------- xhat (already normalized) * g + b -> bf16 ------------------
__global__ __launch_bounds__(256) void affine_bf16_kernel(
    const float* __restrict__ in, const float* __restrict__ g,
    const float* __restrict__ b, unsigned short* __restrict__ out)
{
    int r = blockIdx.x;
    int t = threadIdx.x;
    float4 v = ((const float4*)(in + (long)r * D))[t];
    float4 g4 = ((const float4*)g)[t];
    float4 b4 = ((const float4*)b)[t];
    ushort4 o;
    o.x = f2bf(v.x * g4.x + b4.x);
    o.y = f2bf(v.y * g4.y + b4.y);
    o.z = f2bf(v.z * g4.z + b4.z);
    o.w = f2bf(v.w * g4.w + b4.w);
    ((ushort4*)(out + (long)r * D))[t] = o;
}

// ------------------------ final LN with affine -> out ------------------------
__global__ __launch_bounds__(256) void final_ln_kernel(
    const float* __restrict__ in, const float* __restrict__ g,
    const float* __restrict__ b, float* __restrict__ out)
{
    __shared__ float red[8];
    int r = blockIdx.x;
    int t = threadIdx.x;
    float4 v = ((const float4*)(in + (long)r * D))[t];
    float s  = v.x + v.y + v.z + v.w;
    float ss = v.x*v.x + v.y*v.y + v.z*v.z + v.w*v.w;
    block_reduce_2(s, ss, red);
    float mean = s * (1.0f / D);
    float var  = ss * (1.0f / D) - mean * mean;
    float rstd = rsqrtf(var + EPS);
    float4 g4 = ((const float4*)g)[t];
    float4 b4 = ((const float4*)b)[t];
    float4 o;
    o.x = (v.x - mean) * rstd * g4.x + b4.x;
    o.y = (v.y - mean) * rstd * g4.y + b4.y;
    o.z = (v.z - mean) * rstd * g4.z + b4.z;
    o.w = (v.w - mean) * rstd * g4.w + b4.w;
    ((float4*)(out + (long)r * D))[t] = o;
}

// ---------------------- lat init: broadcast latents to B ---------------------
__global__ __launch_bounds__(256) void lat_init_kernel(
    const float* __restrict__ latents, float* __restrict__ lat)
{
    int r = blockIdx.x;            // b*NL + i
    int i = r % NL;
    int t = threadIdx.x;
    ((float4*)(lat + (long)r * D))[t] = ((const float4*)(latents + (long)i * D))[t];
}

// ------------- weight convert: W f32 [K][N] -> Wt bf16 [N][K] ----------------
// grid (N/64, K/64), 256 threads. lane = n, (t>>6) = 16-k chunk.
__global__ __launch_bounds__(256) void wt_conv_kernel(
    const float* __restrict__ W, unsigned short* __restrict__ Wt, int K, int N)
{
    int n  = blockIdx.x * 64 + (threadIdx.x & 63);
    int k0 = blockIdx.y * 64 + (threadIdx.x >> 6) * 16;
    unsigned short u[16];
#pragma unroll
    for (int j = 0; j < 16; ++j)
        u[j] = f2bf(W[(long)(k0 + j) * N + n]);
    *(uint4*)(Wt + (long)n * K + k0)     = *(uint4*)(u);
    *(uint4*)(Wt + (long)n * K + k0 + 8) = *(uint4*)(u + 8);
}

// ------------------------------ bf16 MFMA GEMM -------------------------------
// C = epilogue( A[Mpad][K]bf16 @ Bt[N][K]bf16^T ), m97 structure:
// 128x128 tile, 4 waves (2x2), BK=64, global_load_lds width 16.
#define MODE_GELU  1   // bf16 gelu store
#define MODE_RES   2   // fp32 residual add
#define MODE_BF16  3   // bf16 store (scaled)
#define MODE_KV    4   // col<512 -> K bf16; col>=512 -> Vt bf16 (transposed)

__global__ __launch_bounds__(256) void gemm_bf16_kernel(
    const unsigned short* __restrict__ A, const unsigned short* __restrict__ Bt,
    void* __restrict__ C, void* __restrict__ C2,
    int M, int N, int K,
    int rpb, long long cbs, int roff, int ldc,
    float scale, int mode)
{
    __shared__ __align__(16) unsigned short As[128 * 64];
    __shared__ __align__(16) unsigned short Bs[128 * 64];
    int tid = threadIdx.x;
    int w = tid >> 6, lane = tid & 63;
    int wm = w >> 1, wn = w & 1;
    int lr = lane & 15, lg = lane >> 4;
    long m0 = (long)blockIdx.x * 128, n0 = (long)blockIdx.y * 128;

    // staging: wave w covers 32 rows (4 calls x 8 rows), lane->(row, 16B chunk)
    const unsigned short* Ag = A + (m0 + w * 32 + (lane >> 3)) * K + (lane & 7) * 8;
    const unsigned short* Bg = Bt + (n0 + w * 32 + (lane >> 3)) * K + (lane & 7) * 8;
    unsigned short* Al = As + w * 2048;
    unsigned short* Bl = Bs + w * 2048;

    f32x4 acc[4][4] = {};

    for (int k0 = 0; k0 < K; k0 += 64) {
        __syncthreads();
#pragma unroll
        for (int i = 0; i < 4; ++i) {
            gload_lds16(Ag + k0 + (long)i * 8 * K, Al + i * 512);
            gload_lds16(Bg + k0 + (long)i * 8 * K, Bl + i * 512);
        }
        __syncthreads();
#pragma unroll
        for (int kk = 0; kk < 2; ++kk) {
            bf16x8 am[4], bn[4];
#pragma unroll
            for (int m = 0; m < 4; ++m)
                am[m] = *(const bf16x8*)(As + (wm * 64 + m * 16 + lr) * 64 + kk * 32 + lg * 8);
#pragma unroll
            for (int n = 0; n < 4; ++n)
                bn[n] = *(const bf16x8*)(Bs + (wn * 64 + n * 16 + lr) * 64 + kk * 32 + lg * 8);
#pragma unroll
            for (int m = 0; m < 4; ++m)
#pragma unroll
                for (int n = 0; n < 4; ++n)
                    acc[m][n] = __builtin_amdgcn_mfma_f32_16x16x32_bf16(am[m], bn[n], acc[m][n], 0, 0, 0);
        }
    }

#pragma unroll
    for (int m = 0; m < 4; ++m) {
        long ar0 = m0 + wm * 64 + m * 16 + lg * 4;
#pragma unroll
        for (int n = 0; n < 4; ++n) {
            long col = n0 + wn * 64 + n * 16 + lr;
            f32x4 v = acc[m][n];
            if (mode == MODE_RES) {
#pragma unroll
                for (int r = 0; r < 4; ++r) {
                    long ar = ar0 + r;
                    if (ar < M) {
                        long bbx = ar / rpb, j = roff + ar % rpb;
                        float* p = (float*)C + bbx * cbs + j * (long)ldc + col;
                        *p += v[r];
                    }
                }
            } else if (mode == MODE_BF16) {
#pragma unroll
                for (int r = 0; r < 4; ++r) {
                    long ar = ar0 + r;
                    if (ar < M) {
                        long bbx = ar / rpb, j = roff + ar % rpb;
                        ((unsigned short*)C)[bbx * cbs + j * (long)ldc + col] = f2bf(v[r] * scale);
                    }
                }
            } else if (mode == MODE_GELU) {
#pragma unroll
                for (int r = 0; r < 4; ++r) {
                    long ar = ar0 + r;
                    if (ar < M) {
                        float val = v[r];
                        val = 0.5f * val * (1.0f + erff(val * 0.70710678118654752f));
                        ((unsigned short*)C)[ar * (long)ldc + col] = f2bf(val);
                    }
                }
            } else { // MODE_KV
                if (col < INNER) {
#pragma unroll
                    for (int r = 0; r < 4; ++r) {
                        long ar = ar0 + r;
                        if (ar < M) {
                            long bbx = ar / rpb, j = roff + ar % rpb;
                            ((unsigned short*)C)[(bbx * FN_PAD + j) * INNER + col] = f2bf(v[r]);
                        }
                    }
                } else {
                    int nn = (int)col - INNER;
                    long j0 = roff + ar0 % rpb;
                    bool fast = (ar0 + 3 < M) && ((ar0 % rpb) + 3 < rpb) && ((j0 & 3) == 0);
                    if (fast) {
                        long bbx = ar0 / rpb;
                        ushort4 pk;
                        pk.x = f2bf(v[0]); pk.y = f2bf(v[1]);
                        pk.z = f2bf(v[2]); pk.w = f2bf(v[3]);
                        *(ushort4*)((unsigned short*)C2 + (bbx * INNER + nn) * FN_PAD + j0) = pk;
                    } else {
#pragma unroll
                        for (int r = 0; r < 4; ++r) {
                            long ar = ar0 + r;
                            if (ar < M) {
                                long bbx = ar / rpb, j = roff + ar % rpb;
                                ((unsigned short*)C2)[(bbx * INNER + nn) * FN_PAD + j] = f2bf(v[r]);
                            }
                        }
                    }
                }
            }
        }
    }
}

// ----------------------- MFMA flash attention --------------------------------
__global__ __launch_bounds__(256) void attn_mfma_kernel(
    const unsigned short* __restrict__ qb, const unsigned short* __restrict__ kb,
    const unsigned short* __restrict__ vt, const int* __restrict__ split,
    unsigned short* __restrict__ o)
{
    int bh = blockIdx.y;
    int b  = bh >> 3;
    int h  = bh & 7;
    int w  = threadIdx.x >> 6;
    int lane = threadIdx.x & 63;
    int q0 = blockIdx.x * 64 + w * 16;
    if (q0 >= NL) return;

    __shared__ unsigned short p_lds[4][16 * 64];   // 2KB per wave, XOR-swizzled
    unsigned short* pl = p_lds[w];

    int lr = lane & 15;
    int lg = lane >> 4;

    bf16x8 qa0, qa1;
    {
        const unsigned short* qrow = qb + ((long)b * NL_PAD + q0 + lr) * INNER + h * 64;
        qa0 = *(const bf16x8*)(qrow + lg * 8);
        qa1 = *(const bf16x8*)(qrow + 32 + lg * 8);
    }

    f32x4 oacc[4] = {{0,0,0,0},{0,0,0,0},{0,0,0,0},{0,0,0,0}};
    float m[4]    = {-1e30f, -1e30f, -1e30f, -1e30f};
    float lsum[4] = {0.f, 0.f, 0.f, 0.f};

    int sp = split[b];
    if (sp < 0) sp = 0;
    if (sp > F) sp = F;
    int ntx = (sp + 63) >> 6;
    int ntot = ntx + 12;

    for (int t = 0; t < ntot; ++t) {
        int j0, limit;
        if (t < ntx) { j0 = t * 64;             limit = sp; }
        else         { j0 = F + (t - ntx) * 64; limit = FN; }

        f32x4 s[4] = {{0,0,0,0},{0,0,0,0},{0,0,0,0},{0,0,0,0}};
        const unsigned short* kbase =
            kb + ((long)b * FN_PAD + j0 + lr) * INNER + h * 64 + lg * 8;
#pragma unroll
        for (int st = 0; st < 4; ++st) {
            bf16x8 kf0 = *(const bf16x8*)(kbase + (long)st * 16 * INNER);
            bf16x8 kf1 = *(const bf16x8*)(kbase + (long)st * 16 * INNER + 32);
            s[st] = __builtin_amdgcn_mfma_f32_16x16x32_bf16(qa0, kf0, s[st], 0, 0, 0);
            s[st] = __builtin_amdgcn_mfma_f32_16x16x32_bf16(qa1, kf1, s[st], 0, 0, 0);
        }

        if (j0 + 64 > limit) {
#pragma unroll
            for (int st = 0; st < 4; ++st) {
                bool valid = (j0 + st * 16 + lr) < limit;
#pragma unroll
                for (int r = 0; r < 4; ++r)
                    s[st][r] = valid ? s[st][r] : -1e30f;
            }
        }

        float tm[4];
#pragma unroll
        for (int r = 0; r < 4; ++r)
            tm[r] = fmaxf(fmaxf(s[0][r], s[1][r]), fmaxf(s[2][r], s[3][r]));
#pragma unroll
        for (int off = 1; off < 16; off <<= 1) {
#pragma unroll
            for (int r = 0; r < 4; ++r)
                tm[r] = fmaxf(tm[r], __shfl_xor(tm[r], off));
        }
        float cr[4];
#pragma unroll
        for (int r = 0; r < 4; ++r) {
            float mn = fmaxf(m[r], tm[r]);
            cr[r] = __expf(m[r] - mn);
            m[r]  = mn;
        }
#pragma unroll
        for (int st = 0; st < 4; ++st)
#pragma unroll
            for (int r = 0; r < 4; ++r)
                s[st][r] = __expf(s[st][r] - m[r]);
        float ts[4];
#pragma unroll
        for (int r = 0; r < 4; ++r)
            ts[r] = (s[0][r] + s[1][r]) + (s[2][r] + s[3][r]);
#pragma unroll
        for (int off = 1; off < 16; off <<= 1) {
#pragma unroll
            for (int r = 0; r < 4; ++r)
                ts[r] += __shfl_xor(ts[r], off);
        }
#pragma unroll
        for (int r = 0; r < 4; ++r)
            lsum[r] = lsum[r] * cr[r] + ts[r];
#pragma unroll
        for (int nst = 0; nst < 4; ++nst)
#pragma unroll
            for (int r = 0; r < 4; ++r)
                oacc[nst][r] *= cr[r];

#pragma unroll
        for (int st = 0; st < 4; ++st)
#pragma unroll
            for (int r = 0; r < 4; ++r) {
                int row  = lg * 4 + r;
                int col  = st * 16 + lr;
                int byte = (row * 128 + col * 2) ^ ((row & 7) << 4);
                *(unsigned short*)((char*)pl + byte) = f2bf(s[st][r]);
            }

#pragma unroll
        for (int kk = 0; kk < 2; ++kk) {
            int row  = lr;
            int byte = (row * 128 + kk * 64 + lg * 16) ^ ((row & 7) << 4);
            bf16x8 pa = *(const bf16x8*)((char*)pl + byte);
#pragma unroll
            for (int nst = 0; nst < 4; ++nst) {
                const unsigned short* vp =
                    vt + ((long)bh * DH + nst * 16 + lr) * FN_PAD + j0 + kk * 32 + lg * 8;
                bf16x8 vf = *(const bf16x8*)vp;
                oacc[nst] = __builtin_amdgcn_mfma_f32_16x16x32_bf16(pa, vf, oacc[nst], 0, 0, 0);
            }
        }
    }

    float inv[4];
#pragma unroll
    for (int r = 0; r < 4; ++r) inv[r] = 1.0f / lsum[r];
#pragma unroll
    for (int nst = 0; nst < 4; ++nst)
#pragma unroll
        for (int r = 0; r < 4; ++r) {
            int row = q0 + lg * 4 + r;
            if (row < NL)
                o[((long)b * NL + row) * INNER + h * 64 + nst * 16 + lr] =
                    f2bf(oacc[nst][r] * inv[r]);
        }
}

// ------------------------------- host side ----------------------------------
static void launch_gemm(const unsigned short* A, const unsigned short* Bt,
                        void* C, void* C2,
                        int M, int N, int K,
                        int rpb, long long cbs, int roff, int ldc,
                        float scale, int mode, hipStream_t s)
{
    dim3 grid((M + 127) / 128, N / 128);
    gemm_bf16_kernel<<<grid, 256, 0, s>>>(A, Bt, C, C2, M, N, K, rpb, cbs, roff, ldc, scale, mode);
}

extern "C" void kernel_launch(void* const* d_in, const int* in_sizes, int n_in,
                              void* d_out, int out_size, void* d_ws, size_t ws_size,
                              hipStream_t stream)
{
    const float* x        = (const float*)d_in[0];
    const int*   split    = (const int*)d_in[1];
    const float* latents  = (const float*)d_in[2];
    const float* sp_emb   = (const float*)d_in[3];
    const float* fr_emb   = (const float*)d_in[4];
    const float* nm_g     = (const float*)d_in[5];
    const float* nm_b     = (const float*)d_in[6];
    const float* nl_g     = (const float*)d_in[7];
    const float* nl_b     = (const float*)d_in[8];
    const float* wq       = (const float*)d_in[9];
    const float* wkv      = (const float*)d_in[10];
    const float* wo       = (const float*)d_in[11];
    const float* ffn_g    = (const float*)d_in[12];
    const float* ffn_b    = (const float*)d_in[13];
    const float* ffw1     = (const float*)d_in[14];
    const float* ffw2     = (const float*)d_in[15];
    const float* final_g  = (const float*)d_in[16];
    const float* final_b  = (const float*)d_in[17];
    float* out = (float*)d_out;

    // ---- workspace layout ----
    float* ws = (float*)d_ws;
    float* xhat = ws;                                  // B*F*D f32
    float* lat  = xhat + (long)B * F * D;              // B*NL*D f32
    unsigned short* ub = (unsigned short*)(lat + (long)B * NL * D);
    unsigned short* la   = ub;                          // MLAT_PAD*D
    unsigned short* fa   = la   + (long)MLAT_PAD * D;
    unsigned short* xa   = fa   + (long)MLAT_PAD * D;   // B*F*D
    unsigned short* h1b  = xa   + (long)B * F * D;      // MLAT_PAD*4D
    unsigned short* ob   = h1b  + (long)MLAT_PAD * 4 * D; // MLAT_PAD*INNER
    unsigned short* qb   = ob   + (long)MLAT_PAD * INNER; // B*NL_PAD*INNER
    unsigned short* kb   = qb   + (long)B * NL_PAD * INNER; // B*FN_PAD*INNER
    unsigned short* vt   = kb   + (long)B * FN_PAD * INNER; // B*INNER*FN_PAD
    unsigned short* wqT  = vt   + (long)B * FN_PAD * INNER; // INNER*D
    unsigned short* wkvT = wqT  + (long)INNER * D;           // 2*INNER*D
    unsigned short* woT  = wkvT + (long)2 * INNER * D;       // D*INNER
    unsigned short* f1T  = woT  + (long)D * INNER;           // 4D*D
    unsigned short* f2T  = f1T  + (long)4 * D * D;           // D*4D

    emb_ln_kernel<<<B * F, 256, 0, stream>>>(x, sp_emb, fr_emb, xhat);
    lat_init_kernel<<<B * NL, 256, 0, stream>>>(latents, lat);

    const int MX = B * F;    // 4224

    for (int l = 0; l < DEPTH; ++l) {
        const float* wq_l   = wq   + (long)l * D * INNER;
        const float* wkv_l  = wkv  + (long)l * D * 2 * INNER;
        const float* wo_l   = wo   + (long)l * INNER * D;
        const float* ffw1_l = ffw1 + (long)l * D * 4 * D;
        const float* ffw2_l = ffw2 + (long)l * 4 * D * D;

        // weight transpose-convert (f32 [K][N] -> bf16 [N][K])
        wt_conv_kernel<<<dim3(INNER / 64, D / 64), 256, 0, stream>>>(wq_l, wqT, D, INNER);
        wt_conv_kernel<<<dim3(2 * INNER / 64, D / 64), 256, 0, stream>>>(wkv_l, wkvT, D, 2 * INNER);
        wt_conv_kernel<<<dim3(D / 64, INNER / 64), 256, 0, stream>>>(wo_l, woT, INNER, D);
        wt_conv_kernel<<<dim3(4 * D / 64, D / 64), 256, 0, stream>>>(ffw1_l, f1T, D, 4 * D);
        wt_conv_kernel<<<dim3(D / 64, 4 * D / 64), 256, 0, stream>>>(ffw2_l, f2T, 4 * D, D);

        // A operands (bf16, affine applied)
        affine_bf16_kernel<<<MX, 256, 0, stream>>>(xhat, nm_g + l * D, nm_b + l * D, xa);
        rownorm_affine_bf16_kernel<<<MLAT, 256, 0, stream>>>(lat, nl_g + l * D, nl_b + l * D, la);

        // q = la @ wq * scale -> bf16 [B][NL_PAD][INNER]
        launch_gemm(la, wqT, qb, nullptr, MLAT, INNER, D,
                    NL, (long long)NL_PAD * INNER, 0, INNER, 0.125f, MODE_BF16, stream);

        // kv: K rows + Vt
        launch_gemm(xa, wkvT, kb, vt, MX, 2 * INNER, D,
                    F, 0, 0, 0, 1.0f, MODE_KV, stream);
        launch_gemm(la, wkvT, kb, vt, MLAT, 2 * INNER, D,
                    NL, 0, F, 0, 1.0f, MODE_KV, stream);

        // attention -> ob bf16
        attn_mfma_kernel<<<dim3((NL + 63) / 64, B * H), 256, 0, stream>>>(
            qb, kb, vt, split, ob);

        // lat += ob @ wo
        launch_gemm(ob, woT, lat, nullptr, MLAT, D, INNER,
                    MLAT, 0, 0, D, 1.0f, MODE_RES, stream);

        // FFN
        rownorm_affine_bf16_kernel<<<MLAT, 256, 0, stream>>>(lat, ffn_g + l * D, ffn_b + l * D, fa);
        launch_gemm(fa, f1T, h1b, nullptr, MLAT, 4 * D, D,
                    MLAT, 0, 0, 4 * D, 1.0f, MODE_GELU, stream);
        launch_gemm(h1b, f2T, lat, nullptr, MLAT, D, 4 * D,
                    MLAT, 0, 0, D, 1.0f, MODE_RES, stream);
    }

    final_ln_kernel<<<MLAT, 256, 0, stream>>>(lat, final_g, final_b, out);
}